// Round 4
// baseline (543.548 us; speedup 1.0000x reference)
//
#include <hip/hip_runtime.h>

// ---------------------------------------------------------------------------
// SelectedUnitsHead (AlphaStar-style pointer head), MI355X / gfx950
// B=256 rows, E=512 entities, 64 autoregressive steps.
// One persistent block (512 thr) per batch row. d_out is fp32.
// v8: BISECT ROUND. v5/v6/v7 all failed with identical ids-absmax=262 even
//     after restoring bit-exact v4 numerics (v7) => deterministic logic bug
//     in one of the shared structural deltas; 3 line-audits failed to find
//     it. This version is v4 VERBATIM + exactly two provably-bit-identical
//     deltas: (1) phase-C kp row read from VGPRs (thread t's own kpT column,
//     values kept at write time; kpT LDS unchanged for phase D), (2) per-
//     thread register entity mask replacing maskv[] (only thread t ever
//     reads maskv[t]). All other v5 deltas (wqT swizzle, LSTM-in-VGPR,
//     vectorized reductions, register xf) deferred — reintroduce one at a
//     time against a passing base.
// ---------------------------------------------------------------------------

#define JAX_PARTITIONABLE 1

typedef unsigned int u32;
typedef _Float16 half2v __attribute__((ext_vector_type(2)));

#define NB 256
#define NE 512
#define NT 64

#define OFF_UNITS 8388608      // 256*64*512   (fp32 elements)
#define OFF_AR    8404992      // + 256*64     (fp32 elements)

// ws layout (float units):
//   Wq[8192] | cvec[256] | xf0[65536] | wk2[4096] | gumbels[8388608]
#define WS_WQ   0
#define WS_CV   8192
#define WS_XF0  8448
#define WS_WK2  73984
#define WS_GU   78080

// barrier with LDS-visibility only (no vmcnt drain of in-flight global stores)
#define BARL() asm volatile("s_waitcnt lgkmcnt(0)\n\ts_barrier" ::: "memory")

struct U2 { u32 a, b; };

__host__ __device__ constexpr u32 rotl32(u32 x, int r) {
  return (x << r) | (x >> (32 - r));
}

__host__ __device__ constexpr U2 tf2x32(u32 k0, u32 k1, u32 x0, u32 x1) {
  u32 ks2 = k0 ^ k1 ^ 0x1BD11BDAu;
  x0 += k0; x1 += k1;
  x0 += x1; x1 = rotl32(x1, 13); x1 ^= x0;
  x0 += x1; x1 = rotl32(x1, 15); x1 ^= x0;
  x0 += x1; x1 = rotl32(x1, 26); x1 ^= x0;
  x0 += x1; x1 = rotl32(x1, 6);  x1 ^= x0;
  x0 += k1; x1 += ks2 + 1u;
  x0 += x1; x1 = rotl32(x1, 17); x1 ^= x0;
  x0 += x1; x1 = rotl32(x1, 29); x1 ^= x0;
  x0 += x1; x1 = rotl32(x1, 16); x1 ^= x0;
  x0 += x1; x1 = rotl32(x1, 24); x1 ^= x0;
  x0 += ks2; x1 += k0 + 2u;
  x0 += x1; x1 = rotl32(x1, 13); x1 ^= x0;
  x0 += x1; x1 = rotl32(x1, 15); x1 ^= x0;
  x0 += x1; x1 = rotl32(x1, 26); x1 ^= x0;
  x0 += x1; x1 = rotl32(x1, 6);  x1 ^= x0;
  x0 += k0; x1 += k1 + 3u;
  x0 += x1; x1 = rotl32(x1, 17); x1 ^= x0;
  x0 += x1; x1 = rotl32(x1, 29); x1 ^= x0;
  x0 += x1; x1 = rotl32(x1, 16); x1 ^= x0;
  x0 += x1; x1 = rotl32(x1, 24); x1 ^= x0;
  x0 += k1; x1 += ks2 + 4u;
  x0 += x1; x1 = rotl32(x1, 13); x1 ^= x0;
  x0 += x1; x1 = rotl32(x1, 15); x1 ^= x0;
  x0 += x1; x1 = rotl32(x1, 26); x1 ^= x0;
  x0 += x1; x1 = rotl32(x1, 6);  x1 ^= x0;
  x0 += ks2; x1 += k0 + 5u;
  return U2{x0, x1};
}

struct KeyTab { u32 s0[NT]; u32 s1[NT]; };

__host__ __device__ constexpr KeyTab make_tab() {
  KeyTab t{};
  u32 k0 = 0u, k1 = 42u;
  for (int i = 0; i < NT; ++i) {
#if JAX_PARTITIONABLE
    U2 nk = tf2x32(k0, k1, 0u, 0u);
    U2 sb = tf2x32(k0, k1, 0u, 1u);
#else
    U2 r02 = tf2x32(k0, k1, 0u, 2u);
    U2 r13 = tf2x32(k0, k1, 1u, 3u);
    U2 nk{r02.a, r13.a};
    U2 sb{r02.b, r13.b};
#endif
    t.s0[i] = sb.a; t.s1[i] = sb.b;
    k0 = nk.a; k1 = nk.b;
  }
  return t;
}

__constant__ KeyTab SUBTAB = make_tab();

__device__ __forceinline__ float gumbel_draw(u32 k0, u32 k1, u32 jf) {
#if JAX_PARTITIONABLE
  U2 v = tf2x32(k0, k1, 0u, jf);
  u32 bits = v.a ^ v.b;
#else
  u32 bits;
  if (jf < 65536u) { U2 v = tf2x32(k0, k1, jf, jf + 65536u); bits = v.a; }
  else             { U2 v = tf2x32(k0, k1, jf - 65536u, jf); bits = v.b; }
#endif
  float f = __uint_as_float((bits >> 9) | 0x3f800000u) - 1.0f;
  float u = f + 1e-20f;
  u = fmaxf(u, 1e-20f);
  return -__logf(-__logf(u));
}

__device__ __forceinline__ float fdot2f(half2v a, half2v b, float c) {
#if __has_builtin(__builtin_amdgcn_fdot2)
  return __builtin_amdgcn_fdot2(a, b, c, false);
#else
  return c + (float)a.x * (float)b.x + (float)a.y * (float)b.y;
#endif
}

// ---------------------------------------------------------------------------
// K0: gumbel precompute — one thread per (b, step, e) draw, active rows only.
// grid 16384 x 512: blk = b*64 + step, tid = e.
// ---------------------------------------------------------------------------
__global__ __launch_bounds__(512) void suh_gum(
    const int* __restrict__ act, const float* __restrict__ selt,
    float* __restrict__ gws)
{
  const u32 blk = blockIdx.x;
  const int b = (int)(blk >> 6), step = (int)(blk & 63u);
  if (selt[act[b]] == 0.0f) return;
  const int e = threadIdx.x;
  gws[((size_t)blk << 9) | (u32)e] =
      gumbel_draw(SUBTAB.s0[step], SUBTAB.s1[step], (u32)(b * 512 + e));
}

// ---------------------------------------------------------------------------
// K1 (grid 290 x 512 thr):
//   blocks 0..255  : xf0[b] = ar0[b]@W1 + b1 + relu(um[a[b]]@Wf + bf)
//   blocks 256..287: Wq row r = Wp[r]@W1
//   block 288      : cvec = bp@W1
//   block 289      : pack Wk fp32 -> f16 pairs into ws[WS_WK2]
// ---------------------------------------------------------------------------
__global__ __launch_bounds__(512) void suh_prep(
    const float* __restrict__ ar0, const int* __restrict__ act,
    const float* __restrict__ Wf, const float* __restrict__ bfv,
    const float* __restrict__ W1, const float* __restrict__ b1,
    const float* __restrict__ Wp, const float* __restrict__ bp,
    const float* __restrict__ Wk, const float* __restrict__ umt,
    float* __restrict__ ws)
{
  __shared__ float lvec[1024];
  __shared__ float red2[512];
  __shared__ float feL[256];
  __shared__ float lum[256];
  const int t = threadIdx.x;
  const int bid = blockIdx.x;

  if (bid >= 289) {                      // block 289: Wk f16 pack
    half2v* wkp = (half2v*)(ws + WS_WK2);
    #pragma unroll
    for (int i = 0; i < 8; ++i) {
      const int p = t * 8 + i;           // p in [0,4096)
      const int c2 = p >> 5, h = p & 31; // channel pair c2 -> (2c2, 2c2+1)
      half2v v = { (_Float16)Wk[c2 * 64 + h], (_Float16)Wk[c2 * 64 + 32 + h] };
      wkp[p] = v;
    }
    return;
  }

  const int o = t & 255, hf = t >> 8;
  const float* src;
  if (bid < NB) src = ar0 + bid * 1024;
  else if (bid < NB + 32) src = Wp + (bid - NB) * 1024;
  else src = bp;

  for (int i = t; i < 1024; i += 512) lvec[i] = src[i];
  if (bid < NB && t < 256) lum[t] = umt[act[bid] * 256 + t];
  __syncthreads();

  float p = 0.0f;
  const int kb = hf * 512;
  #pragma unroll 16
  for (int k = 0; k < 512; ++k) p = fmaf(lvec[kb + k], W1[(kb + k) * 256 + o], p);
  red2[hf * 256 + o] = p;
  if (bid < NB && hf == 1) {
    float fe = bfv[o];
    #pragma unroll 8
    for (int k = 0; k < 256; ++k) fe = fmaf(lum[k], Wf[k * 256 + o], fe);
    feL[o] = fmaxf(fe, 0.0f);
  }
  __syncthreads();

  if (t < 256) {
    const float s = red2[t] + red2[256 + t];
    if (bid < NB)            ws[WS_XF0 + bid * 256 + t] = s + b1[t] + feL[t];
    else if (bid < NB + 32)  ws[WS_WQ + (bid - NB) * 256 + t] = s;
    else                     ws[WS_CV + t] = s;
  }
}

// ---------------------------------------------------------------------------
// K2: one block per batch row; 64 autoregressive steps, 5 light barriers/step.
// ---------------------------------------------------------------------------
__global__ __launch_bounds__(512, 1) void suh_main(
    const float* __restrict__ ar0, const int* __restrict__ act,
    const float* __restrict__ emb, const float* __restrict__ bk,
    const float* __restrict__ W2, const float* __restrict__ b2,
    const float* __restrict__ Wx, const float* __restrict__ Wh,
    const float* __restrict__ bl, const float* __restrict__ Wp,
    const float* __restrict__ bp, const float* __restrict__ selt,
    const float* __restrict__ ws, const float* __restrict__ gws,
    const int use_pre, float* __restrict__ outp)
{
  const int b = blockIdx.x;
  const int t = threadIdx.x;
  const float sel = selt[act[b]];
  float* outL = outp;
  float* outU = outp + OFF_UNITS;
  float* outA = outp + OFF_AR;

  if (sel == 0.0f) {
    float4 z4 = {0.0f, 0.0f, 0.0f, 0.0f};
    float4* pl = (float4*)(outL + (size_t)b * 32768);
    for (int i = t; i < 8192; i += 512) pl[i] = z4;
    if (t < 16) ((float4*)(outU + b * 64))[t] = z4;
    if (t < 256) ((float4*)(outA + b * 1024))[t] = z4;
    return;
  }

  __shared__ half2v kpT[16][NE];        // 32 KB transposed kp: [h-pair][entity]
  __shared__ float wq[32][256];         // 32 KB Wq = Wp@W1
  __shared__ half2v whx[4096];          // 16 KB {Wx,Wh} pairs: [r][gatecol]
  __shared__ float xf[256];
  __shared__ float red[512];
  __shared__ float cvs[256];
  __shared__ float sacc[32];
  __shared__ half2v h2b[16];
  __shared__ float wsum[8];
  __shared__ float wargv[8];
  __shared__ int   wargi[8];

  // ---- per-thread register weights (phase A) ------------------------------
  const int hh = t & 31, kc = t >> 5;
  float w2r[16];
  #pragma unroll
  for (int i = 0; i < 16; ++i) w2r[i] = W2[(kc * 16 + i) * 32 + hh];

  float blv0 = 0.0f, blv1 = 0.0f, b2v = 0.0f;
  float hv = 0.0f, cv = 0.0f;           // LSTM state in wave0 lanes 0..31
  if (t < 64) { blv0 = bl[t]; blv1 = bl[64 + t]; b2v = b2[t & 31]; }

  // ---- LDS fills ----------------------------------------------------------
  for (int i = t; i < 4096; i += 512) {
    const int r = i >> 7, g = i & 127;
    half2v v = { (_Float16)Wx[r * 128 + g], (_Float16)Wh[r * 128 + g] };
    whx[i] = v;
  }
  {
    const float4* s4 = (const float4*)(ws + WS_WQ);
    float4* d4 = (float4*)&wq[0][0];
    for (int i = t; i < 2048; i += 512) d4[i] = s4[i];
  }
  if (t < 256) { xf[t] = ws[WS_XF0 + b * 256 + t]; cvs[t] = ws[WS_CV + t]; }
  if (t < 32) sacc[t] = 0.0f;
  float mymask = 1.0f;                  // v8: register mask (was maskv[t] LDS)

  // ---- key_proj row e=t via fdot2, written transposed; keep kpr in VGPRs --
  half2v kpr[16];                       // v8: own column kept in registers
  {
    float acc[32];
    #pragma unroll
    for (int h = 0; h < 32; ++h) acc[h] = bk[h];
    const float4* erow = (const float4*)(emb + (size_t)b * (NE * 256) + (size_t)t * 256);
    const half2v* wkg = (const half2v*)(ws + WS_WK2);
    for (int c4 = 0; c4 < 64; ++c4) {
      float4 ev = erow[c4];
      half2v e01 = { (_Float16)ev.x, (_Float16)ev.y };
      half2v e23 = { (_Float16)ev.z, (_Float16)ev.w };
      const half2v* w0 = wkg + (2 * c4) * 32;
      const half2v* w1 = w0 + 32;
      #pragma unroll
      for (int h = 0; h < 32; ++h) {
        acc[h] = fdot2f(e01, w0[h], acc[h]);
        acc[h] = fdot2f(e23, w1[h], acc[h]);
      }
    }
    #pragma unroll
    for (int j = 0; j < 16; ++j) {
      half2v v = { (_Float16)acc[2 * j], (_Float16)acc[2 * j + 1] };
      kpr[j] = v;
      kpT[j][t] = v;
    }
  }
  __syncthreads();

  const size_t gbase = (size_t)b * 64 * 512 + t;

  for (int step = 0; step < NT; ++step) {
    // gumbel: precomputed load (issued early, used after B3) or fallback
    float gum;
    if (use_pre) gum = gws[gbase + (size_t)step * 512];
    else gum = gumbel_draw(SUBTAB.s0[step], SUBTAB.s1[step], (u32)(b * 512 + t));

    // ---- A: z2 partials: relu(xf) @ W2 ------------------------------------
    {
      float pa = 0.0f;
      const float* xk = &xf[kc * 16];
      #pragma unroll
      for (int i = 0; i < 16; ++i) pa = fmaf(fmaxf(xk[i], 0.0f), w2r[i], pa);
      red[kc * 32 + hh] = pa;
    }
    BARL();                                            // B1

    // ---- B: wave0: z2 reduce + LSTM (weights from LDS, f16 pairs) ---------
    if (t < 64) {
      const int h = t & 31, half = t >> 5;
      float z = 0.0f;
      #pragma unroll
      for (int i = 0; i < 8; ++i) z += red[(half * 8 + i) * 32 + h];
      z += __shfl_xor(z, 32);
      const float z2v = z + b2v;

      float g0 = blv0, g1 = blv1;
      #pragma unroll
      for (int r = 0; r < 32; ++r) {
        const float zr = __shfl(z2v, r);
        const float hr = __shfl(hv, r);
        half2v p0 = whx[r * 128 + t];
        half2v p1 = whx[r * 128 + 64 + t];
        g0 = fmaf(zr, (float)p0.x, g0); g0 = fmaf(hr, (float)p0.y, g0);
        g1 = fmaf(zr, (float)p1.x, g1); g1 = fmaf(hr, (float)p1.y, g1);
      }
      const float zf = __shfl_xor(g0, 32);
      const float zo = __shfl_xor(g1, 32);
      if (t < 32) {
        const float si = 1.0f / (1.0f + __expf(-g0));
        const float sf = 1.0f / (1.0f + __expf(-zf));
        const float so = 1.0f / (1.0f + __expf(-zo));
        cv = sf * cv + si * tanhf(g1);
        hv = so * tanhf(cv);
      }
      const float ha = __shfl(hv, 2 * (t & 31));
      const float hb = __shfl(hv, 2 * (t & 31) + 1);
      if (t < 16) { half2v v = { (_Float16)ha, (_Float16)hb }; h2b[t] = v; }
    }
    BARL();                                            // B2

    // ---- C: logits (register kp row), exp, per-wave sum -------------------
    float a0 = 0.0f, a1 = 0.0f, a2 = 0.0f, a3 = 0.0f;
    #pragma unroll
    for (int j = 0; j < 16; j += 4) {
      a0 = fdot2f(kpr[j],     h2b[j],     a0);
      a1 = fdot2f(kpr[j + 1], h2b[j + 1], a1);
      a2 = fdot2f(kpr[j + 2], h2b[j + 2], a2);
      a3 = fdot2f(kpr[j + 3], h2b[j + 3], a3);
    }
    const float y2 = ((a0 + a1) + (a2 + a3)) * mymask;
    outL[(size_t)b * 32768 + step * 512 + t] = y2;
    const float ev = __expf(y2);
    float sv = ev;
    #pragma unroll
    for (int s = 1; s < 64; s <<= 1) sv += __shfl_xor(sv, s);
    if ((t & 63) == 0) wsum[t >> 6] = sv;
    BARL();                                            // B3

    float Z = wsum[0];
    #pragma unroll
    for (int i = 1; i < 8; ++i) Z += wsum[i];
    float val = ev / Z + gum;
    int idx = t;
    #pragma unroll
    for (int s = 1; s < 64; s <<= 1) {
      const float vo = __shfl_xor(val, s);
      const int io = __shfl_xor(idx, s);
      if (vo > val || (vo == val && io < idx)) { val = vo; idx = io; }
    }
    if ((t & 63) == 0) { wargv[t >> 6] = val; wargi[t >> 6] = idx; }
    BARL();                                            // B4

    float bvv = wargv[0]; int id = wargi[0];
    #pragma unroll
    for (int i = 1; i < 8; ++i) {
      if (wargv[i] > bvv || (wargv[i] == bvv && wargi[i] < id)) { bvv = wargv[i]; id = wargi[i]; }
    }

    // ---- D: mask, outputs, xf feedback ------------------------------------
    if (t == id) mymask = 0.0f;
    if (t == 0) outU[b * 64 + step] = (float)id;
    if (t < 32) {
      half2v kj = kpT[t >> 1][id];
      const float kv = (t & 1) ? (float)kj.y : (float)kj.x;
      sacc[t] += kv - 0.001953125f;
    }
    if (t < 256) {
      float dx = cvs[t];
      #pragma unroll
      for (int j = 0; j < 16; ++j) {
        half2v kj = kpT[j][id];
        dx = fmaf((float)kj.x - 0.001953125f, wq[2 * j][t], dx);
        dx = fmaf((float)kj.y - 0.001953125f, wq[2 * j + 1][t], dx);
      }
      xf[t] += dx;
    }
    BARL();                                            // B5
  }

  // ---- epilogue: ar = ar0 + sacc@Wp + 64*bp -------------------------------
  for (int j = t; j < 1024; j += 512) {
    float acc2 = ar0[b * 1024 + j] + 64.0f * bp[j];
    #pragma unroll 8
    for (int r = 0; r < 32; ++r) acc2 = fmaf(sacc[r], Wp[r * 1024 + j], acc2);
    outA[b * 1024 + j] = acc2;
  }
}

extern "C" void kernel_launch(void* const* d_in, const int* in_sizes, int n_in,
                              void* d_out, int out_size, void* d_ws, size_t ws_size,
                              hipStream_t stream)
{
  (void)in_sizes; (void)n_in; (void)out_size;
  const float* ar0 = (const float*)d_in[0];
  const int*   act = (const int*)d_in[1];
  const float* emb = (const float*)d_in[2];
  const float* Wf  = (const float*)d_in[3];
  const float* bfv = (const float*)d_in[4];
  const float* Wk  = (const float*)d_in[5];
  const float* bk  = (const float*)d_in[6];
  const float* W1  = (const float*)d_in[7];
  const float* b1  = (const float*)d_in[8];
  const float* W2  = (const float*)d_in[9];
  const float* b2  = (const float*)d_in[10];
  const float* Wx  = (const float*)d_in[11];
  const float* Wh  = (const float*)d_in[12];
  const float* bl  = (const float*)d_in[13];
  const float* Wp  = (const float*)d_in[14];
  const float* bp  = (const float*)d_in[15];
  const float* umt = (const float*)d_in[16];
  const float* selt = (const float*)d_in[17];
  float* ws = (float*)d_ws;
  float* outp = (float*)d_out;

  const size_t need = (size_t)(WS_GU + 8388608) * sizeof(float);
  const int use_pre = (ws_size >= need) ? 1 : 0;

  suh_prep<<<dim3(290), dim3(512), 0, stream>>>(ar0, act, Wf, bfv, W1, b1, Wp, bp, Wk, umt, ws);
  if (use_pre)
    suh_gum<<<dim3(16384), dim3(512), 0, stream>>>(act, selt, ws + WS_GU);
  suh_main<<<dim3(256), dim3(512), 0, stream>>>(ar0, act, emb, bk, W2, b2, Wx, Wh,
                                                bl, Wp, bp, selt, ws, ws + WS_GU,
                                                use_pre, outp);
}

// Round 5
// 531.782 us; speedup vs baseline: 1.0221x; 1.0221x over previous
//
#include <hip/hip_runtime.h>

// ---------------------------------------------------------------------------
// SelectedUnitsHead (AlphaStar-style pointer head), MI355X / gfx950
// B=256 rows, E=512 entities, 64 autoregressive steps.
// One persistent block (512 thr) per batch row. d_out is fp32.
// v9: v8 (PASSED, 543us) + two deltas:
//  (1) DPP wave-argmax: 4 VALU DPP stages (xor1,xor2,ror4,ror8) + 2 shfl.
//      Argmax with min-idx tiebreak is assoc+comm => bit-identical ids for
//      any tree shape. Sum butterfly + Z stay byte-identical (no numeric
//      change anywhere this round).
//  (2) LSTM weights in VGPRs (w0r/w1r) replacing whx LDS; __shfl broadcasts
//      kept exactly as v8. Value-equal by index algebra
//      (whx[r*128+t] == {Wx[r*128+t],Wh[r*128+t]} == w0r[r]).
//      This is also the bisect probe for the v5/v6/v7 mystery failure.
// Model: step is dependent-latency bound (1 blk/CU, 2 waves/SIMD): wave0
// serial LSTM chain + three 6-stage bpermute butterflies + 5 barriers.
// ---------------------------------------------------------------------------

#define JAX_PARTITIONABLE 1

typedef unsigned int u32;
typedef _Float16 half2v __attribute__((ext_vector_type(2)));

#define NB 256
#define NE 512
#define NT 64

#define OFF_UNITS 8388608      // 256*64*512   (fp32 elements)
#define OFF_AR    8404992      // + 256*64     (fp32 elements)

// ws layout (float units):
//   Wq[8192] | cvec[256] | xf0[65536] | wk2[4096] | gumbels[8388608]
#define WS_WQ   0
#define WS_CV   8192
#define WS_XF0  8448
#define WS_WK2  73984
#define WS_GU   78080

// barrier with LDS-visibility only (no vmcnt drain of in-flight global stores)
#define BARL() asm volatile("s_waitcnt lgkmcnt(0)\n\ts_barrier" ::: "memory")

struct U2 { u32 a, b; };

__host__ __device__ constexpr u32 rotl32(u32 x, int r) {
  return (x << r) | (x >> (32 - r));
}

__host__ __device__ constexpr U2 tf2x32(u32 k0, u32 k1, u32 x0, u32 x1) {
  u32 ks2 = k0 ^ k1 ^ 0x1BD11BDAu;
  x0 += k0; x1 += k1;
  x0 += x1; x1 = rotl32(x1, 13); x1 ^= x0;
  x0 += x1; x1 = rotl32(x1, 15); x1 ^= x0;
  x0 += x1; x1 = rotl32(x1, 26); x1 ^= x0;
  x0 += x1; x1 = rotl32(x1, 6);  x1 ^= x0;
  x0 += k1; x1 += ks2 + 1u;
  x0 += x1; x1 = rotl32(x1, 17); x1 ^= x0;
  x0 += x1; x1 = rotl32(x1, 29); x1 ^= x0;
  x0 += x1; x1 = rotl32(x1, 16); x1 ^= x0;
  x0 += x1; x1 = rotl32(x1, 24); x1 ^= x0;
  x0 += ks2; x1 += k0 + 2u;
  x0 += x1; x1 = rotl32(x1, 13); x1 ^= x0;
  x0 += x1; x1 = rotl32(x1, 15); x1 ^= x0;
  x0 += x1; x1 = rotl32(x1, 26); x1 ^= x0;
  x0 += x1; x1 = rotl32(x1, 6);  x1 ^= x0;
  x0 += k0; x1 += k1 + 3u;
  x0 += x1; x1 = rotl32(x1, 17); x1 ^= x0;
  x0 += x1; x1 = rotl32(x1, 29); x1 ^= x0;
  x0 += x1; x1 = rotl32(x1, 16); x1 ^= x0;
  x0 += x1; x1 = rotl32(x1, 24); x1 ^= x0;
  x0 += k1; x1 += ks2 + 4u;
  x0 += x1; x1 = rotl32(x1, 13); x1 ^= x0;
  x0 += x1; x1 = rotl32(x1, 15); x1 ^= x0;
  x0 += x1; x1 = rotl32(x1, 26); x1 ^= x0;
  x0 += x1; x1 = rotl32(x1, 6);  x1 ^= x0;
  x0 += ks2; x1 += k0 + 5u;
  return U2{x0, x1};
}

struct KeyTab { u32 s0[NT]; u32 s1[NT]; };

__host__ __device__ constexpr KeyTab make_tab() {
  KeyTab t{};
  u32 k0 = 0u, k1 = 42u;
  for (int i = 0; i < NT; ++i) {
#if JAX_PARTITIONABLE
    U2 nk = tf2x32(k0, k1, 0u, 0u);
    U2 sb = tf2x32(k0, k1, 0u, 1u);
#else
    U2 r02 = tf2x32(k0, k1, 0u, 2u);
    U2 r13 = tf2x32(k0, k1, 1u, 3u);
    U2 nk{r02.a, r13.a};
    U2 sb{r02.b, r13.b};
#endif
    t.s0[i] = sb.a; t.s1[i] = sb.b;
    k0 = nk.a; k1 = nk.b;
  }
  return t;
}

__constant__ KeyTab SUBTAB = make_tab();

__device__ __forceinline__ float gumbel_draw(u32 k0, u32 k1, u32 jf) {
#if JAX_PARTITIONABLE
  U2 v = tf2x32(k0, k1, 0u, jf);
  u32 bits = v.a ^ v.b;
#else
  u32 bits;
  if (jf < 65536u) { U2 v = tf2x32(k0, k1, jf, jf + 65536u); bits = v.a; }
  else             { U2 v = tf2x32(k0, k1, jf - 65536u, jf); bits = v.b; }
#endif
  float f = __uint_as_float((bits >> 9) | 0x3f800000u) - 1.0f;
  float u = f + 1e-20f;
  u = fmaxf(u, 1e-20f);
  return -__logf(-__logf(u));
}

__device__ __forceinline__ float fdot2f(half2v a, half2v b, float c) {
#if __has_builtin(__builtin_amdgcn_fdot2)
  return __builtin_amdgcn_fdot2(a, b, c, false);
#else
  return c + (float)a.x * (float)b.x + (float)a.y * (float)b.y;
#endif
}

// ---- argmax helpers --------------------------------------------------------

__device__ __forceinline__ void amax_comb(float& v, int& i, float vo, int io) {
  if (vo > v || (vo == v && io < i)) { v = vo; i = io; }
}

__device__ __forceinline__ void amax_sh(float& v, int& i, int m) {
  float vo = __shfl_xor(v, m);
  int io = __shfl_xor(i, m);
  amax_comb(v, i, vo, io);
}

#if __has_builtin(__builtin_amdgcn_mov_dpp)
#define HAVE_DPP 1
template <int CTRL>
__device__ __forceinline__ void amax_dpp(float& v, int& i) {
  float vo = __int_as_float(
      __builtin_amdgcn_mov_dpp(__float_as_int(v), CTRL, 0xF, 0xF, true));
  int io = __builtin_amdgcn_mov_dpp(i, CTRL, 0xF, 0xF, true);
  amax_comb(v, i, vo, io);
}
#endif

// argmax (first-index tiebreak) over the 64-lane wave, result in all lanes.
// (max, min-idx-tie) combine is associative+commutative => result is
// bit-identical for ANY reduction tree, incl. the DPP tree below.
__device__ __forceinline__ void wave_amax(float& v, int& i) {
#ifdef HAVE_DPP
  amax_dpp<0xB1>(v, i);     // quad_perm [1,0,3,2]  (xor 1)
  amax_dpp<0x4E>(v, i);     // quad_perm [2,3,0,1]  (xor 2)
  amax_dpp<0x124>(v, i);    // row_ror:4
  amax_dpp<0x128>(v, i);    // row_ror:8  -> full 16-lane row reduced
  amax_sh(v, i, 16);
  amax_sh(v, i, 32);
#else
  #pragma unroll
  for (int s = 1; s < 64; s <<= 1) amax_sh(v, i, s);
#endif
}

// ---------------------------------------------------------------------------
// K0: gumbel precompute — one thread per (b, step, e) draw, active rows only.
// grid 16384 x 512: blk = b*64 + step, tid = e.
// ---------------------------------------------------------------------------
__global__ __launch_bounds__(512) void suh_gum(
    const int* __restrict__ act, const float* __restrict__ selt,
    float* __restrict__ gws)
{
  const u32 blk = blockIdx.x;
  const int b = (int)(blk >> 6), step = (int)(blk & 63u);
  if (selt[act[b]] == 0.0f) return;
  const int e = threadIdx.x;
  gws[((size_t)blk << 9) | (u32)e] =
      gumbel_draw(SUBTAB.s0[step], SUBTAB.s1[step], (u32)(b * 512 + e));
}

// ---------------------------------------------------------------------------
// K1 (grid 290 x 512 thr):
//   blocks 0..255  : xf0[b] = ar0[b]@W1 + b1 + relu(um[a[b]]@Wf + bf)
//   blocks 256..287: Wq row r = Wp[r]@W1
//   block 288      : cvec = bp@W1
//   block 289      : pack Wk fp32 -> f16 pairs into ws[WS_WK2]
// ---------------------------------------------------------------------------
__global__ __launch_bounds__(512) void suh_prep(
    const float* __restrict__ ar0, const int* __restrict__ act,
    const float* __restrict__ Wf, const float* __restrict__ bfv,
    const float* __restrict__ W1, const float* __restrict__ b1,
    const float* __restrict__ Wp, const float* __restrict__ bp,
    const float* __restrict__ Wk, const float* __restrict__ umt,
    float* __restrict__ ws)
{
  __shared__ float lvec[1024];
  __shared__ float red2[512];
  __shared__ float feL[256];
  __shared__ float lum[256];
  const int t = threadIdx.x;
  const int bid = blockIdx.x;

  if (bid >= 289) {                      // block 289: Wk f16 pack
    half2v* wkp = (half2v*)(ws + WS_WK2);
    #pragma unroll
    for (int i = 0; i < 8; ++i) {
      const int p = t * 8 + i;           // p in [0,4096)
      const int c2 = p >> 5, h = p & 31; // channel pair c2 -> (2c2, 2c2+1)
      half2v v = { (_Float16)Wk[c2 * 64 + h], (_Float16)Wk[c2 * 64 + 32 + h] };
      wkp[p] = v;
    }
    return;
  }

  const int o = t & 255, hf = t >> 8;
  const float* src;
  if (bid < NB) src = ar0 + bid * 1024;
  else if (bid < NB + 32) src = Wp + (bid - NB) * 1024;
  else src = bp;

  for (int i = t; i < 1024; i += 512) lvec[i] = src[i];
  if (bid < NB && t < 256) lum[t] = umt[act[bid] * 256 + t];
  __syncthreads();

  float p = 0.0f;
  const int kb = hf * 512;
  #pragma unroll 16
  for (int k = 0; k < 512; ++k) p = fmaf(lvec[kb + k], W1[(kb + k) * 256 + o], p);
  red2[hf * 256 + o] = p;
  if (bid < NB && hf == 1) {
    float fe = bfv[o];
    #pragma unroll 8
    for (int k = 0; k < 256; ++k) fe = fmaf(lum[k], Wf[k * 256 + o], fe);
    feL[o] = fmaxf(fe, 0.0f);
  }
  __syncthreads();

  if (t < 256) {
    const float s = red2[t] + red2[256 + t];
    if (bid < NB)            ws[WS_XF0 + bid * 256 + t] = s + b1[t] + feL[t];
    else if (bid < NB + 32)  ws[WS_WQ + (bid - NB) * 256 + t] = s;
    else                     ws[WS_CV + t] = s;
  }
}

// ---------------------------------------------------------------------------
// K2: one block per batch row; 64 autoregressive steps, 5 light barriers/step.
// ---------------------------------------------------------------------------
__global__ __launch_bounds__(512, 1) void suh_main(
    const float* __restrict__ ar0, const int* __restrict__ act,
    const float* __restrict__ emb, const float* __restrict__ bk,
    const float* __restrict__ W2, const float* __restrict__ b2,
    const float* __restrict__ Wx, const float* __restrict__ Wh,
    const float* __restrict__ bl, const float* __restrict__ Wp,
    const float* __restrict__ bp, const float* __restrict__ selt,
    const float* __restrict__ ws, const float* __restrict__ gws,
    const int use_pre, float* __restrict__ outp)
{
  const int b = blockIdx.x;
  const int t = threadIdx.x;
  const float sel = selt[act[b]];
  float* outL = outp;
  float* outU = outp + OFF_UNITS;
  float* outA = outp + OFF_AR;

  if (sel == 0.0f) {
    float4 z4 = {0.0f, 0.0f, 0.0f, 0.0f};
    float4* pl = (float4*)(outL + (size_t)b * 32768);
    for (int i = t; i < 8192; i += 512) pl[i] = z4;
    if (t < 16) ((float4*)(outU + b * 64))[t] = z4;
    if (t < 256) ((float4*)(outA + b * 1024))[t] = z4;
    return;
  }

  __shared__ half2v kpT[16][NE];        // 32 KB transposed kp: [h-pair][entity]
  __shared__ float wq[32][256];         // 32 KB Wq = Wp@W1
  __shared__ float xf[256];
  __shared__ float red[512];
  __shared__ float cvs[256];
  __shared__ float sacc[32];
  __shared__ half2v h2b[16];
  __shared__ float wsum[8];
  __shared__ float wargv[8];
  __shared__ int   wargi[8];

  // ---- per-thread register weights (phase A) ------------------------------
  const int hh = t & 31, kc = t >> 5;
  float w2r[16];
  #pragma unroll
  for (int i = 0; i < 16; ++i) w2r[i] = W2[(kc * 16 + i) * 32 + hh];

  float blv0 = 0.0f, blv1 = 0.0f, b2v = 0.0f;
  float hv = 0.0f, cv = 0.0f;           // LSTM state in wave0 lanes 0..31
  if (t < 64) { blv0 = bl[t]; blv1 = bl[64 + t]; b2v = b2[t & 31]; }

  // ---- v9: LSTM weights into wave0 registers (f16 pairs {Wx,Wh}) ----------
  // Value-equal to v8's whx LDS: whx[r*128+t] == {Wx[r*128+t], Wh[r*128+t]}.
  half2v w0r[32], w1r[32];
  if (t < 64) {
    #pragma unroll
    for (int r = 0; r < 32; ++r) {
      w0r[r] = half2v{ (_Float16)Wx[r * 128 + t],      (_Float16)Wh[r * 128 + t] };
      w1r[r] = half2v{ (_Float16)Wx[r * 128 + 64 + t], (_Float16)Wh[r * 128 + 64 + t] };
    }
  }

  // ---- LDS fills ----------------------------------------------------------
  {
    const float4* s4 = (const float4*)(ws + WS_WQ);
    float4* d4 = (float4*)&wq[0][0];
    for (int i = t; i < 2048; i += 512) d4[i] = s4[i];
  }
  if (t < 256) { xf[t] = ws[WS_XF0 + b * 256 + t]; cvs[t] = ws[WS_CV + t]; }
  if (t < 32) sacc[t] = 0.0f;
  float mymask = 1.0f;                  // register mask (v8-proven)

  // ---- key_proj row e=t via fdot2, written transposed; keep kpr in VGPRs --
  half2v kpr[16];                       // own column kept in registers (v8)
  {
    float acc[32];
    #pragma unroll
    for (int h = 0; h < 32; ++h) acc[h] = bk[h];
    const float4* erow = (const float4*)(emb + (size_t)b * (NE * 256) + (size_t)t * 256);
    const half2v* wkg = (const half2v*)(ws + WS_WK2);
    for (int c4 = 0; c4 < 64; ++c4) {
      float4 ev = erow[c4];
      half2v e01 = { (_Float16)ev.x, (_Float16)ev.y };
      half2v e23 = { (_Float16)ev.z, (_Float16)ev.w };
      const half2v* w0 = wkg + (2 * c4) * 32;
      const half2v* w1 = w0 + 32;
      #pragma unroll
      for (int h = 0; h < 32; ++h) {
        acc[h] = fdot2f(e01, w0[h], acc[h]);
        acc[h] = fdot2f(e23, w1[h], acc[h]);
      }
    }
    #pragma unroll
    for (int j = 0; j < 16; ++j) {
      half2v v = { (_Float16)acc[2 * j], (_Float16)acc[2 * j + 1] };
      kpr[j] = v;
      kpT[j][t] = v;
    }
  }
  __syncthreads();

  const size_t gbase = (size_t)b * 64 * 512 + t;

  for (int step = 0; step < NT; ++step) {
    // gumbel: precomputed load (issued at step top, used after B3) or fallback
    float gum;
    if (use_pre) gum = gws[gbase + (size_t)step * 512];
    else gum = gumbel_draw(SUBTAB.s0[step], SUBTAB.s1[step], (u32)(b * 512 + t));

    // ---- A: z2 partials: relu(xf) @ W2 ------------------------------------
    {
      float pa = 0.0f;
      const float* xk = &xf[kc * 16];
      #pragma unroll
      for (int i = 0; i < 16; ++i) pa = fmaf(fmaxf(xk[i], 0.0f), w2r[i], pa);
      red[kc * 32 + hh] = pa;
    }
    BARL();                                            // B1

    // ---- B: wave0: z2 reduce + LSTM (weights from VGPRs, v9) --------------
    if (t < 64) {
      const int h = t & 31, half = t >> 5;
      float z = 0.0f;
      #pragma unroll
      for (int i = 0; i < 8; ++i) z += red[(half * 8 + i) * 32 + h];
      z += __shfl_xor(z, 32);
      const float z2v = z + b2v;

      float g0 = blv0, g1 = blv1;
      #pragma unroll
      for (int r = 0; r < 32; ++r) {
        const float zr = __shfl(z2v, r);
        const float hr = __shfl(hv, r);
        half2v p0 = w0r[r];
        half2v p1 = w1r[r];
        g0 = fmaf(zr, (float)p0.x, g0); g0 = fmaf(hr, (float)p0.y, g0);
        g1 = fmaf(zr, (float)p1.x, g1); g1 = fmaf(hr, (float)p1.y, g1);
      }
      const float zf = __shfl_xor(g0, 32);
      const float zo = __shfl_xor(g1, 32);
      if (t < 32) {
        const float si = 1.0f / (1.0f + __expf(-g0));
        const float sf = 1.0f / (1.0f + __expf(-zf));
        const float so = 1.0f / (1.0f + __expf(-zo));
        cv = sf * cv + si * tanhf(g1);
        hv = so * tanhf(cv);
      }
      const float ha = __shfl(hv, 2 * (t & 31));
      const float hb = __shfl(hv, 2 * (t & 31) + 1);
      if (t < 16) { half2v v = { (_Float16)ha, (_Float16)hb }; h2b[t] = v; }
    }
    BARL();                                            // B2

    // ---- C: logits (register kp row), exp, per-wave sum -------------------
    float a0 = 0.0f, a1 = 0.0f, a2 = 0.0f, a3 = 0.0f;
    #pragma unroll
    for (int j = 0; j < 16; j += 4) {
      a0 = fdot2f(kpr[j],     h2b[j],     a0);
      a1 = fdot2f(kpr[j + 1], h2b[j + 1], a1);
      a2 = fdot2f(kpr[j + 2], h2b[j + 2], a2);
      a3 = fdot2f(kpr[j + 3], h2b[j + 3], a3);
    }
    const float y2 = ((a0 + a1) + (a2 + a3)) * mymask;
    outL[(size_t)b * 32768 + step * 512 + t] = y2;
    const float ev = __expf(y2);
    float sv = ev;
    #pragma unroll
    for (int s = 1; s < 64; s <<= 1) sv += __shfl_xor(sv, s);
    if ((t & 63) == 0) wsum[t >> 6] = sv;
    BARL();                                            // B3

    float Z = wsum[0];
    #pragma unroll
    for (int i = 1; i < 8; ++i) Z += wsum[i];
    float val = ev / Z + gum;
    int idx = t;
    wave_amax(val, idx);                               // v9: DPP tree (bit-exact)
    if ((t & 63) == 0) { wargv[t >> 6] = val; wargi[t >> 6] = idx; }
    BARL();                                            // B4

    float bvv = wargv[0]; int id = wargi[0];
    #pragma unroll
    for (int i = 1; i < 8; ++i) {
      if (wargv[i] > bvv || (wargv[i] == bvv && wargi[i] < id)) { bvv = wargv[i]; id = wargi[i]; }
    }

    // ---- D: mask, outputs, xf feedback ------------------------------------
    if (t == id) mymask = 0.0f;
    if (t == 0) outU[b * 64 + step] = (float)id;
    if (t < 32) {
      half2v kj = kpT[t >> 1][id];
      const float kv = (t & 1) ? (float)kj.y : (float)kj.x;
      sacc[t] += kv - 0.001953125f;
    }
    if (t < 256) {
      float dx = cvs[t];
      #pragma unroll
      for (int j = 0; j < 16; ++j) {
        half2v kj = kpT[j][id];
        dx = fmaf((float)kj.x - 0.001953125f, wq[2 * j][t], dx);
        dx = fmaf((float)kj.y - 0.001953125f, wq[2 * j + 1][t], dx);
      }
      xf[t] += dx;
    }
    BARL();                                            // B5
  }

  // ---- epilogue: ar = ar0 + sacc@Wp + 64*bp -------------------------------
  for (int j = t; j < 1024; j += 512) {
    float acc2 = ar0[b * 1024 + j] + 64.0f * bp[j];
    #pragma unroll 8
    for (int r = 0; r < 32; ++r) acc2 = fmaf(sacc[r], Wp[r * 1024 + j], acc2);
    outA[b * 1024 + j] = acc2;
  }
}

extern "C" void kernel_launch(void* const* d_in, const int* in_sizes, int n_in,
                              void* d_out, int out_size, void* d_ws, size_t ws_size,
                              hipStream_t stream)
{
  (void)in_sizes; (void)n_in; (void)out_size;
  const float* ar0 = (const float*)d_in[0];
  const int*   act = (const int*)d_in[1];
  const float* emb = (const float*)d_in[2];
  const float* Wf  = (const float*)d_in[3];
  const float* bfv = (const float*)d_in[4];
  const float* Wk  = (const float*)d_in[5];
  const float* bk  = (const float*)d_in[6];
  const float* W1  = (const float*)d_in[7];
  const float* b1  = (const float*)d_in[8];
  const float* W2  = (const float*)d_in[9];
  const float* b2  = (const float*)d_in[10];
  const float* Wx  = (const float*)d_in[11];
  const float* Wh  = (const float*)d_in[12];
  const float* bl  = (const float*)d_in[13];
  const float* Wp  = (const float*)d_in[14];
  const float* bp  = (const float*)d_in[15];
  const float* umt = (const float*)d_in[16];
  const float* selt = (const float*)d_in[17];
  float* ws = (float*)d_ws;
  float* outp = (float*)d_out;

  const size_t need = (size_t)(WS_GU + 8388608) * sizeof(float);
  const int use_pre = (ws_size >= need) ? 1 : 0;

  suh_prep<<<dim3(290), dim3(512), 0, stream>>>(ar0, act, Wf, bfv, W1, b1, Wp, bp, Wk, umt, ws);
  if (use_pre)
    suh_gum<<<dim3(16384), dim3(512), 0, stream>>>(act, selt, ws + WS_GU);
  suh_main<<<dim3(256), dim3(512), 0, stream>>>(ar0, act, emb, bk, W2, b2, Wx, Wh,
                                                bl, Wp, bp, selt, ws, ws + WS_GU,
                                                use_pre, outp);
}

// Round 8
// 484.490 us; speedup vs baseline: 1.1219x; 1.0976x over previous
//
#include <hip/hip_runtime.h>

// ---------------------------------------------------------------------------
// SelectedUnitsHead (AlphaStar-style pointer head), MI355X / gfx950
// B=256 rows, E=512 entities, 64 autoregressive steps.
// One persistent block (512 thr) per batch row. d_out is fp32.
// v10 (RESUBMIT x2 — R6/R7 were infra failures: "container failed twice",
// no kernel signal either round; harness push path was already degrading on
// passing rounds R3-R5 (push_in_npz_s 0 -> 850s). Kernel audited for hang
// risk: all barriers uniform, no unbounded loops, no OOB => resubmitting
// unchanged per no-signal re-run discipline):
//  (1) suh_gum kernel ELIMINATED: gumbel computed inline in main between
//      B1 and B2 (hidden under wave0's serial LSTM). Waves 1-7 compute own
//      draws; wave1 also computes wave0's 64 draws -> gumL[] LDS (written
//      pre-B2-barrier, read post-B3 => ordering safe). Bit-identical values
//      (same gumbel_draw fn+args). Kills 16384-blk launch + 33MB WS RT.
//      Also a direct measurement of the constant ~230us total-main gap.
//  (2) DPP wave-sum reusing v9's hardware-verified amax tree (xor1/xor2/
//      ror4/ror8 + 2 shfl). Rotation tree = complete sum (each quad counted
//      once); rounding-level only; single Z from lane0 shared by all lanes.
//  (3) v_readlane broadcasts in wave0's LSTM loop (replaces 64 serial-path
//      ds_bpermutes with SALU reads; all wave0 lanes active; lanes 0..31
//      hold valid z2v/hv). Also bisects the most-entangled v7 suspect.
// Avoided (v5/v6/v7 mystery-bug suspect set): wqT4 swizzle, kpRM layout,
// h2bu vec-reads, register-xfr, u32x2 reads.
// ---------------------------------------------------------------------------

#define JAX_PARTITIONABLE 1

typedef unsigned int u32;
typedef _Float16 half2v __attribute__((ext_vector_type(2)));

#define NB 256
#define NE 512
#define NT 64

#define OFF_UNITS 8388608      // 256*64*512   (fp32 elements)
#define OFF_AR    8404992      // + 256*64     (fp32 elements)

// ws layout (float units):
//   Wq[8192] | cvec[256] | xf0[65536] | wk2[4096]
#define WS_WQ   0
#define WS_CV   8192
#define WS_XF0  8448
#define WS_WK2  73984

// barrier with LDS-visibility only (no vmcnt drain of in-flight global stores)
#define BARL() asm volatile("s_waitcnt lgkmcnt(0)\n\ts_barrier" ::: "memory")

struct U2 { u32 a, b; };

__host__ __device__ constexpr u32 rotl32(u32 x, int r) {
  return (x << r) | (x >> (32 - r));
}

__host__ __device__ constexpr U2 tf2x32(u32 k0, u32 k1, u32 x0, u32 x1) {
  u32 ks2 = k0 ^ k1 ^ 0x1BD11BDAu;
  x0 += k0; x1 += k1;
  x0 += x1; x1 = rotl32(x1, 13); x1 ^= x0;
  x0 += x1; x1 = rotl32(x1, 15); x1 ^= x0;
  x0 += x1; x1 = rotl32(x1, 26); x1 ^= x0;
  x0 += x1; x1 = rotl32(x1, 6);  x1 ^= x0;
  x0 += k1; x1 += ks2 + 1u;
  x0 += x1; x1 = rotl32(x1, 17); x1 ^= x0;
  x0 += x1; x1 = rotl32(x1, 29); x1 ^= x0;
  x0 += x1; x1 = rotl32(x1, 16); x1 ^= x0;
  x0 += x1; x1 = rotl32(x1, 24); x1 ^= x0;
  x0 += ks2; x1 += k0 + 2u;
  x0 += x1; x1 = rotl32(x1, 13); x1 ^= x0;
  x0 += x1; x1 = rotl32(x1, 15); x1 ^= x0;
  x0 += x1; x1 = rotl32(x1, 26); x1 ^= x0;
  x0 += x1; x1 = rotl32(x1, 6);  x1 ^= x0;
  x0 += k0; x1 += k1 + 3u;
  x0 += x1; x1 = rotl32(x1, 17); x1 ^= x0;
  x0 += x1; x1 = rotl32(x1, 29); x1 ^= x0;
  x0 += x1; x1 = rotl32(x1, 16); x1 ^= x0;
  x0 += x1; x1 = rotl32(x1, 24); x1 ^= x0;
  x0 += k1; x1 += ks2 + 4u;
  x0 += x1; x1 = rotl32(x1, 13); x1 ^= x0;
  x0 += x1; x1 = rotl32(x1, 15); x1 ^= x0;
  x0 += x1; x1 = rotl32(x1, 26); x1 ^= x0;
  x0 += x1; x1 = rotl32(x1, 6);  x1 ^= x0;
  x0 += ks2; x1 += k0 + 5u;
  return U2{x0, x1};
}

struct KeyTab { u32 s0[NT]; u32 s1[NT]; };

__host__ __device__ constexpr KeyTab make_tab() {
  KeyTab t{};
  u32 k0 = 0u, k1 = 42u;
  for (int i = 0; i < NT; ++i) {
#if JAX_PARTITIONABLE
    U2 nk = tf2x32(k0, k1, 0u, 0u);
    U2 sb = tf2x32(k0, k1, 0u, 1u);
#else
    U2 r02 = tf2x32(k0, k1, 0u, 2u);
    U2 r13 = tf2x32(k0, k1, 1u, 3u);
    U2 nk{r02.a, r13.a};
    U2 sb{r02.b, r13.b};
#endif
    t.s0[i] = sb.a; t.s1[i] = sb.b;
    k0 = nk.a; k1 = nk.b;
  }
  return t;
}

__constant__ KeyTab SUBTAB = make_tab();

__device__ __forceinline__ float gumbel_draw(u32 k0, u32 k1, u32 jf) {
#if JAX_PARTITIONABLE
  U2 v = tf2x32(k0, k1, 0u, jf);
  u32 bits = v.a ^ v.b;
#else
  u32 bits;
  if (jf < 65536u) { U2 v = tf2x32(k0, k1, jf, jf + 65536u); bits = v.a; }
  else             { U2 v = tf2x32(k0, k1, jf - 65536u, jf); bits = v.b; }
#endif
  float f = __uint_as_float((bits >> 9) | 0x3f800000u) - 1.0f;
  float u = f + 1e-20f;
  u = fmaxf(u, 1e-20f);
  return -__logf(-__logf(u));
}

__device__ __forceinline__ float fdot2f(half2v a, half2v b, float c) {
#if __has_builtin(__builtin_amdgcn_fdot2)
  return __builtin_amdgcn_fdot2(a, b, c, false);
#else
  return c + (float)a.x * (float)b.x + (float)a.y * (float)b.y;
#endif
}

__device__ __forceinline__ float rlf(float x, int l) {
#if __has_builtin(__builtin_amdgcn_readlane)
  return __int_as_float(__builtin_amdgcn_readlane(__float_as_int(x), l));
#else
  return __shfl(x, l);
#endif
}

// ---- reduction helpers -----------------------------------------------------

__device__ __forceinline__ void amax_comb(float& v, int& i, float vo, int io) {
  if (vo > v || (vo == v && io < i)) { v = vo; i = io; }
}

__device__ __forceinline__ void amax_sh(float& v, int& i, int m) {
  float vo = __shfl_xor(v, m);
  int io = __shfl_xor(i, m);
  amax_comb(v, i, vo, io);
}

#if __has_builtin(__builtin_amdgcn_mov_dpp)
#define HAVE_DPP 1
template <int CTRL>
__device__ __forceinline__ void amax_dpp(float& v, int& i) {
  float vo = __int_as_float(
      __builtin_amdgcn_mov_dpp(__float_as_int(v), CTRL, 0xF, 0xF, true));
  int io = __builtin_amdgcn_mov_dpp(i, CTRL, 0xF, 0xF, true);
  amax_comb(v, i, vo, io);
}
template <int CTRL>
__device__ __forceinline__ float dpp_addf(float x) {
  return x + __int_as_float(
      __builtin_amdgcn_mov_dpp(__float_as_int(x), CTRL, 0xF, 0xF, true));
}
#endif

// argmax (first-index tiebreak) over the 64-lane wave, result in all lanes.
// assoc+comm combine => bit-identical for any tree (v9-verified on HW).
__device__ __forceinline__ void wave_amax(float& v, int& i) {
#ifdef HAVE_DPP
  amax_dpp<0xB1>(v, i);     // quad_perm [1,0,3,2]  (xor 1)
  amax_dpp<0x4E>(v, i);     // quad_perm [2,3,0,1]  (xor 2)
  amax_dpp<0x124>(v, i);    // row_ror:4
  amax_dpp<0x128>(v, i);    // row_ror:8  -> full 16-lane row reduced
  amax_sh(v, i, 16);
  amax_sh(v, i, 32);
#else
  #pragma unroll
  for (int s = 1; s < 64; s <<= 1) amax_sh(v, i, s);
#endif
}

// full 64-lane sum, all lanes get the total. Same tree as wave_amax
// (HW-verified in v9). Rotation stages: after xor1+xor2 each lane holds its
// quad sum; ror4 adds quad q-1, ror8 adds quads q-2,q-3 => all 4 quads once.
__device__ __forceinline__ float wave_sum(float x) {
#ifdef HAVE_DPP
  x = dpp_addf<0xB1>(x);
  x = dpp_addf<0x4E>(x);
  x = dpp_addf<0x124>(x);
  x = dpp_addf<0x128>(x);
  x += __shfl_xor(x, 16);
  x += __shfl_xor(x, 32);
#else
  #pragma unroll
  for (int s = 1; s < 64; s <<= 1) x += __shfl_xor(x, s);
#endif
  return x;
}

// ---------------------------------------------------------------------------
// K1 (grid 290 x 512 thr):
//   blocks 0..255  : xf0[b] = ar0[b]@W1 + b1 + relu(um[a[b]]@Wf + bf)
//   blocks 256..287: Wq row r = Wp[r]@W1
//   block 288      : cvec = bp@W1
//   block 289      : pack Wk fp32 -> f16 pairs into ws[WS_WK2]
// ---------------------------------------------------------------------------
__global__ __launch_bounds__(512) void suh_prep(
    const float* __restrict__ ar0, const int* __restrict__ act,
    const float* __restrict__ Wf, const float* __restrict__ bfv,
    const float* __restrict__ W1, const float* __restrict__ b1,
    const float* __restrict__ Wp, const float* __restrict__ bp,
    const float* __restrict__ Wk, const float* __restrict__ umt,
    float* __restrict__ ws)
{
  __shared__ float lvec[1024];
  __shared__ float red2[512];
  __shared__ float feL[256];
  __shared__ float lum[256];
  const int t = threadIdx.x;
  const int bid = blockIdx.x;

  if (bid >= 289) {                      // block 289: Wk f16 pack
    half2v* wkp = (half2v*)(ws + WS_WK2);
    #pragma unroll
    for (int i = 0; i < 8; ++i) {
      const int p = t * 8 + i;           // p in [0,4096)
      const int c2 = p >> 5, h = p & 31; // channel pair c2 -> (2c2, 2c2+1)
      half2v v = { (_Float16)Wk[c2 * 64 + h], (_Float16)Wk[c2 * 64 + 32 + h] };
      wkp[p] = v;
    }
    return;
  }

  const int o = t & 255, hf = t >> 8;
  const float* src;
  if (bid < NB) src = ar0 + bid * 1024;
  else if (bid < NB + 32) src = Wp + (bid - NB) * 1024;
  else src = bp;

  for (int i = t; i < 1024; i += 512) lvec[i] = src[i];
  if (bid < NB && t < 256) lum[t] = umt[act[bid] * 256 + t];
  __syncthreads();

  float p = 0.0f;
  const int kb = hf * 512;
  #pragma unroll 16
  for (int k = 0; k < 512; ++k) p = fmaf(lvec[kb + k], W1[(kb + k) * 256 + o], p);
  red2[hf * 256 + o] = p;
  if (bid < NB && hf == 1) {
    float fe = bfv[o];
    #pragma unroll 8
    for (int k = 0; k < 256; ++k) fe = fmaf(lum[k], Wf[k * 256 + o], fe);
    feL[o] = fmaxf(fe, 0.0f);
  }
  __syncthreads();

  if (t < 256) {
    const float s = red2[t] + red2[256 + t];
    if (bid < NB)            ws[WS_XF0 + bid * 256 + t] = s + b1[t] + feL[t];
    else if (bid < NB + 32)  ws[WS_WQ + (bid - NB) * 256 + t] = s;
    else                     ws[WS_CV + t] = s;
  }
}

// ---------------------------------------------------------------------------
// K2: one block per batch row; 64 autoregressive steps, 5 light barriers/step.
// ---------------------------------------------------------------------------
__global__ __launch_bounds__(512, 1) void suh_main(
    const float* __restrict__ ar0, const int* __restrict__ act,
    const float* __restrict__ emb, const float* __restrict__ bk,
    const float* __restrict__ W2, const float* __restrict__ b2,
    const float* __restrict__ Wx, const float* __restrict__ Wh,
    const float* __restrict__ bl, const float* __restrict__ Wp,
    const float* __restrict__ bp, const float* __restrict__ selt,
    const float* __restrict__ ws, float* __restrict__ outp)
{
  const int b = blockIdx.x;
  const int t = threadIdx.x;
  const float sel = selt[act[b]];
  float* outL = outp;
  float* outU = outp + OFF_UNITS;
  float* outA = outp + OFF_AR;

  if (sel == 0.0f) {
    float4 z4 = {0.0f, 0.0f, 0.0f, 0.0f};
    float4* pl = (float4*)(outL + (size_t)b * 32768);
    for (int i = t; i < 8192; i += 512) pl[i] = z4;
    if (t < 16) ((float4*)(outU + b * 64))[t] = z4;
    if (t < 256) ((float4*)(outA + b * 1024))[t] = z4;
    return;
  }

  __shared__ half2v kpT[16][NE];        // 32 KB transposed kp: [h-pair][entity]
  __shared__ float wq[32][256];         // 32 KB Wq = Wp@W1
  __shared__ float xf[256];
  __shared__ float red[512];
  __shared__ float cvs[256];
  __shared__ float sacc[32];
  __shared__ half2v h2b[16];
  __shared__ float gumL[64];            // v10: wave0's gumbels (by wave1)
  __shared__ float wsum[8];
  __shared__ float wargv[8];
  __shared__ int   wargi[8];

  // ---- per-thread register weights (phase A) ------------------------------
  const int hh = t & 31, kc = t >> 5;
  float w2r[16];
  #pragma unroll
  for (int i = 0; i < 16; ++i) w2r[i] = W2[(kc * 16 + i) * 32 + hh];

  float blv0 = 0.0f, blv1 = 0.0f, b2v = 0.0f;
  float hv = 0.0f, cv = 0.0f;           // LSTM state in wave0 lanes 0..31
  if (t < 64) { blv0 = bl[t]; blv1 = bl[64 + t]; b2v = b2[t & 31]; }

  // ---- LSTM weights into wave0 registers (f16 pairs {Wx,Wh}) --------------
  half2v w0r[32], w1r[32];
  if (t < 64) {
    #pragma unroll
    for (int r = 0; r < 32; ++r) {
      w0r[r] = half2v{ (_Float16)Wx[r * 128 + t],      (_Float16)Wh[r * 128 + t] };
      w1r[r] = half2v{ (_Float16)Wx[r * 128 + 64 + t], (_Float16)Wh[r * 128 + 64 + t] };
    }
  }

  // ---- LDS fills ----------------------------------------------------------
  {
    const float4* s4 = (const float4*)(ws + WS_WQ);
    float4* d4 = (float4*)&wq[0][0];
    for (int i = t; i < 2048; i += 512) d4[i] = s4[i];
  }
  if (t < 256) { xf[t] = ws[WS_XF0 + b * 256 + t]; cvs[t] = ws[WS_CV + t]; }
  if (t < 32) sacc[t] = 0.0f;
  float mymask = 1.0f;                  // register mask (v8-proven)

  // ---- key_proj row e=t via fdot2, written transposed; keep kpr in VGPRs --
  half2v kpr[16];
  {
    float acc[32];
    #pragma unroll
    for (int h = 0; h < 32; ++h) acc[h] = bk[h];
    const float4* erow = (const float4*)(emb + (size_t)b * (NE * 256) + (size_t)t * 256);
    const half2v* wkg = (const half2v*)(ws + WS_WK2);
    for (int c4 = 0; c4 < 64; ++c4) {
      float4 ev = erow[c4];
      half2v e01 = { (_Float16)ev.x, (_Float16)ev.y };
      half2v e23 = { (_Float16)ev.z, (_Float16)ev.w };
      const half2v* w0 = wkg + (2 * c4) * 32;
      const half2v* w1 = w0 + 32;
      #pragma unroll
      for (int h = 0; h < 32; ++h) {
        acc[h] = fdot2f(e01, w0[h], acc[h]);
        acc[h] = fdot2f(e23, w1[h], acc[h]);
      }
    }
    #pragma unroll
    for (int j = 0; j < 16; ++j) {
      half2v v = { (_Float16)acc[2 * j], (_Float16)acc[2 * j + 1] };
      kpr[j] = v;
      kpT[j][t] = v;
    }
  }
  __syncthreads();

  for (int step = 0; step < NT; ++step) {
    // ---- A: z2 partials: relu(xf) @ W2 ------------------------------------
    {
      float pa = 0.0f;
      const float* xk = &xf[kc * 16];
      #pragma unroll
      for (int i = 0; i < 16; ++i) pa = fmaf(fmaxf(xk[i], 0.0f), w2r[i], pa);
      red[kc * 32 + hh] = pa;
    }
    BARL();                                            // B1

    // ---- B: wave0: z2 reduce + LSTM (VGPR weights, readlane bcast) --------
    if (t < 64) {
      const int h = t & 31, half = t >> 5;
      float z = 0.0f;
      #pragma unroll
      for (int i = 0; i < 8; ++i) z += red[(half * 8 + i) * 32 + h];
      z += __shfl_xor(z, 32);
      const float z2v = z + b2v;

      float g0 = blv0, g1 = blv1;
      #pragma unroll
      for (int r = 0; r < 32; ++r) {
        const float zr = rlf(z2v, r);
        const float hr = rlf(hv, r);
        half2v p0 = w0r[r];
        half2v p1 = w1r[r];
        g0 = fmaf(zr, (float)p0.x, g0); g0 = fmaf(hr, (float)p0.y, g0);
        g1 = fmaf(zr, (float)p1.x, g1); g1 = fmaf(hr, (float)p1.y, g1);
      }
      const float zf = __shfl_xor(g0, 32);
      const float zo = __shfl_xor(g1, 32);
      if (t < 32) {
        const float si = 1.0f / (1.0f + __expf(-g0));
        const float sf = 1.0f / (1.0f + __expf(-zf));
        const float so = 1.0f / (1.0f + __expf(-zo));
        cv = sf * cv + si * tanhf(g1);
        hv = so * tanhf(cv);
      }
      const float ha = __shfl(hv, 2 * (t & 31));
      const float hb = __shfl(hv, 2 * (t & 31) + 1);
      if (t < 16) { half2v v = { (_Float16)ha, (_Float16)hb }; h2b[t] = v; }
    }

    // ---- v10: inline gumbel for waves 1..7, hidden under wave0's phase B.
    // Wave1 also produces wave0's 64 draws into gumL (visible after B2).
    float gum = 0.0f;
    if (t >= 64) {
      gum = gumbel_draw(SUBTAB.s0[step], SUBTAB.s1[step], (u32)(b * 512 + t));
      if (t < 128)
        gumL[t - 64] = gumbel_draw(SUBTAB.s0[step], SUBTAB.s1[step],
                                   (u32)(b * 512 + (t - 64)));
    }
    BARL();                                            // B2

    // ---- C: logits (register kp row), exp, DPP wave sum -------------------
    float a0 = 0.0f, a1 = 0.0f, a2 = 0.0f, a3 = 0.0f;
    #pragma unroll
    for (int j = 0; j < 16; j += 4) {
      a0 = fdot2f(kpr[j],     h2b[j],     a0);
      a1 = fdot2f(kpr[j + 1], h2b[j + 1], a1);
      a2 = fdot2f(kpr[j + 2], h2b[j + 2], a2);
      a3 = fdot2f(kpr[j + 3], h2b[j + 3], a3);
    }
    const float y2 = ((a0 + a1) + (a2 + a3)) * mymask;
    outL[(size_t)b * 32768 + step * 512 + t] = y2;
    const float ev = __expf(y2);
    float sv = wave_sum(ev);
    if ((t & 63) == 0) wsum[t >> 6] = sv;
    BARL();                                            // B3

    if (t < 64) gum = gumL[t];                         // v10: wave0 draws
    float Z = wsum[0];
    #pragma unroll
    for (int i = 1; i < 8; ++i) Z += wsum[i];
    float val = ev / Z + gum;
    int idx = t;
    wave_amax(val, idx);
    if ((t & 63) == 0) { wargv[t >> 6] = val; wargi[t >> 6] = idx; }
    BARL();                                            // B4

    float bvv = wargv[0]; int id = wargi[0];
    #pragma unroll
    for (int i = 1; i < 8; ++i) {
      if (wargv[i] > bvv || (wargv[i] == bvv && wargi[i] < id)) { bvv = wargv[i]; id = wargi[i]; }
    }

    // ---- D: mask, outputs, xf feedback ------------------------------------
    if (t == id) mymask = 0.0f;
    if (t == 0) outU[b * 64 + step] = (float)id;
    if (t < 32) {
      half2v kj = kpT[t >> 1][id];
      const float kv = (t & 1) ? (float)kj.y : (float)kj.x;
      sacc[t] += kv - 0.001953125f;
    }
    if (t < 256) {
      float dx = cvs[t];
      #pragma unroll
      for (int j = 0; j < 16; ++j) {
        half2v kj = kpT[j][id];
        dx = fmaf((float)kj.x - 0.001953125f, wq[2 * j][t], dx);
        dx = fmaf((float)kj.y - 0.001953125f, wq[2 * j + 1][t], dx);
      }
      xf[t] += dx;
    }
    BARL();                                            // B5
  }

  // ---- epilogue: ar = ar0 + sacc@Wp + 64*bp -------------------------------
  for (int j = t; j < 1024; j += 512) {
    float acc2 = ar0[b * 1024 + j] + 64.0f * bp[j];
    #pragma unroll 8
    for (int r = 0; r < 32; ++r) acc2 = fmaf(sacc[r], Wp[r * 1024 + j], acc2);
    outA[b * 1024 + j] = acc2;
  }
}

extern "C" void kernel_launch(void* const* d_in, const int* in_sizes, int n_in,
                              void* d_out, int out_size, void* d_ws, size_t ws_size,
                              hipStream_t stream)
{
  (void)in_sizes; (void)n_in; (void)out_size; (void)ws_size;
  const float* ar0 = (const float*)d_in[0];
  const int*   act = (const int*)d_in[1];
  const float* emb = (const float*)d_in[2];
  const float* Wf  = (const float*)d_in[3];
  const float* bfv = (const float*)d_in[4];
  const float* Wk  = (const float*)d_in[5];
  const float* bk  = (const float*)d_in[6];
  const float* W1  = (const float*)d_in[7];
  const float* b1  = (const float*)d_in[8];
  const float* W2  = (const float*)d_in[9];
  const float* b2  = (const float*)d_in[10];
  const float* Wx  = (const float*)d_in[11];
  const float* Wh  = (const float*)d_in[12];
  const float* bl  = (const float*)d_in[13];
  const float* Wp  = (const float*)d_in[14];
  const float* bp  = (const float*)d_in[15];
  const float* umt = (const float*)d_in[16];
  const float* selt = (const float*)d_in[17];
  float* ws = (float*)d_ws;
  float* outp = (float*)d_out;

  suh_prep<<<dim3(290), dim3(512), 0, stream>>>(ar0, act, Wf, bfv, W1, b1, Wp, bp, Wk, umt, ws);
  suh_main<<<dim3(256), dim3(512), 0, stream>>>(ar0, act, emb, bk, W2, b2, Wx, Wh,
                                                bl, Wp, bp, selt, ws, outp);
}

// Round 9
// 448.603 us; speedup vs baseline: 1.2116x; 1.0800x over previous
//
#include <hip/hip_runtime.h>

// ---------------------------------------------------------------------------
// SelectedUnitsHead (AlphaStar-style pointer head), MI355X / gfx950
// B=256 rows, E=512 entities, 64 autoregressive steps.
// One persistent block (512 thr) per batch row. d_out is fp32.
// v11: v10 (PASSED, 484.5us total / 271us main) + three latency deltas:
//  (1) wave_sum/wave_amax completed with DPP row_bcast15/31 (0x142/0x143):
//      total lands in lane 63, ZERO ds_bpermute in the trees (was 4/step at
//      ~120cy). Argmax bit-exact (assoc+comm, any tree). Sum: lane63 =
//      (A3+A2)+(A1+A0) == v10's (A0+A1)+(A2+A3) by FP-add commutativity =>
//      Z bit-exact. Lane 63 writes the per-wave LDS slots.
//  (2) fast activations on wave0's serial chain: rcp-sigmoid + exp-identity
//      tanh (saturates correctly). ~1e-7 h perturbation -> ~1e-9 val shift;
//      flip risk ~1e-4 (v7 proved these were NOT the v5-era failure cause).
//  (3) b128 loads of wsum/wargv/wargi with v10's exact sequential combine
//      order (bit-exact); arrays now __align__(16).
// Everything else byte-identical to v10.
// ---------------------------------------------------------------------------

#define JAX_PARTITIONABLE 1

typedef unsigned int u32;
typedef _Float16 half2v __attribute__((ext_vector_type(2)));
typedef float f4 __attribute__((ext_vector_type(4)));
typedef int i32x4 __attribute__((ext_vector_type(4)));

#define NB 256
#define NE 512
#define NT 64

#define OFF_UNITS 8388608      // 256*64*512   (fp32 elements)
#define OFF_AR    8404992      // + 256*64     (fp32 elements)

// ws layout (float units):
//   Wq[8192] | cvec[256] | xf0[65536] | wk2[4096]
#define WS_WQ   0
#define WS_CV   8192
#define WS_XF0  8448
#define WS_WK2  73984

// barrier with LDS-visibility only (no vmcnt drain of in-flight global stores)
#define BARL() asm volatile("s_waitcnt lgkmcnt(0)\n\ts_barrier" ::: "memory")

struct U2 { u32 a, b; };

__host__ __device__ constexpr u32 rotl32(u32 x, int r) {
  return (x << r) | (x >> (32 - r));
}

__host__ __device__ constexpr U2 tf2x32(u32 k0, u32 k1, u32 x0, u32 x1) {
  u32 ks2 = k0 ^ k1 ^ 0x1BD11BDAu;
  x0 += k0; x1 += k1;
  x0 += x1; x1 = rotl32(x1, 13); x1 ^= x0;
  x0 += x1; x1 = rotl32(x1, 15); x1 ^= x0;
  x0 += x1; x1 = rotl32(x1, 26); x1 ^= x0;
  x0 += x1; x1 = rotl32(x1, 6);  x1 ^= x0;
  x0 += k1; x1 += ks2 + 1u;
  x0 += x1; x1 = rotl32(x1, 17); x1 ^= x0;
  x0 += x1; x1 = rotl32(x1, 29); x1 ^= x0;
  x0 += x1; x1 = rotl32(x1, 16); x1 ^= x0;
  x0 += x1; x1 = rotl32(x1, 24); x1 ^= x0;
  x0 += ks2; x1 += k0 + 2u;
  x0 += x1; x1 = rotl32(x1, 13); x1 ^= x0;
  x0 += x1; x1 = rotl32(x1, 15); x1 ^= x0;
  x0 += x1; x1 = rotl32(x1, 26); x1 ^= x0;
  x0 += x1; x1 = rotl32(x1, 6);  x1 ^= x0;
  x0 += k0; x1 += k1 + 3u;
  x0 += x1; x1 = rotl32(x1, 17); x1 ^= x0;
  x0 += x1; x1 = rotl32(x1, 29); x1 ^= x0;
  x0 += x1; x1 = rotl32(x1, 16); x1 ^= x0;
  x0 += x1; x1 = rotl32(x1, 24); x1 ^= x0;
  x0 += k1; x1 += ks2 + 4u;
  x0 += x1; x1 = rotl32(x1, 13); x1 ^= x0;
  x0 += x1; x1 = rotl32(x1, 15); x1 ^= x0;
  x0 += x1; x1 = rotl32(x1, 26); x1 ^= x0;
  x0 += x1; x1 = rotl32(x1, 6);  x1 ^= x0;
  x0 += ks2; x1 += k0 + 5u;
  return U2{x0, x1};
}

struct KeyTab { u32 s0[NT]; u32 s1[NT]; };

__host__ __device__ constexpr KeyTab make_tab() {
  KeyTab t{};
  u32 k0 = 0u, k1 = 42u;
  for (int i = 0; i < NT; ++i) {
#if JAX_PARTITIONABLE
    U2 nk = tf2x32(k0, k1, 0u, 0u);
    U2 sb = tf2x32(k0, k1, 0u, 1u);
#else
    U2 r02 = tf2x32(k0, k1, 0u, 2u);
    U2 r13 = tf2x32(k0, k1, 1u, 3u);
    U2 nk{r02.a, r13.a};
    U2 sb{r02.b, r13.b};
#endif
    t.s0[i] = sb.a; t.s1[i] = sb.b;
    k0 = nk.a; k1 = nk.b;
  }
  return t;
}

__constant__ KeyTab SUBTAB = make_tab();

__device__ __forceinline__ float gumbel_draw(u32 k0, u32 k1, u32 jf) {
#if JAX_PARTITIONABLE
  U2 v = tf2x32(k0, k1, 0u, jf);
  u32 bits = v.a ^ v.b;
#else
  u32 bits;
  if (jf < 65536u) { U2 v = tf2x32(k0, k1, jf, jf + 65536u); bits = v.a; }
  else             { U2 v = tf2x32(k0, k1, jf - 65536u, jf); bits = v.b; }
#endif
  float f = __uint_as_float((bits >> 9) | 0x3f800000u) - 1.0f;
  float u = f + 1e-20f;
  u = fmaxf(u, 1e-20f);
  return -__logf(-__logf(u));
}

__device__ __forceinline__ float fdot2f(half2v a, half2v b, float c) {
#if __has_builtin(__builtin_amdgcn_fdot2)
  return __builtin_amdgcn_fdot2(a, b, c, false);
#else
  return c + (float)a.x * (float)b.x + (float)a.y * (float)b.y;
#endif
}

__device__ __forceinline__ float rlf(float x, int l) {
#if __has_builtin(__builtin_amdgcn_readlane)
  return __int_as_float(__builtin_amdgcn_readlane(__float_as_int(x), l));
#else
  return __shfl(x, l);
#endif
}

__device__ __forceinline__ float fast_rcp(float x) {
#if __has_builtin(__builtin_amdgcn_rcpf)
  return __builtin_amdgcn_rcpf(x);
#else
  return 1.0f / x;
#endif
}

// sigmoid via v_rcp (rel err ~1e-7 vs exact division)
__device__ __forceinline__ float sigm_f(float x) {
  return fast_rcp(1.0f + __expf(-x));
}
// tanh(x) = 1 - 2/(exp(2x)+1); saturates correctly at +/-inf, NaN-free.
__device__ __forceinline__ float tanh_f(float x) {
  return 1.0f - 2.0f * fast_rcp(1.0f + __expf(2.0f * x));
}

// ---- reduction helpers -----------------------------------------------------

__device__ __forceinline__ void amax_comb(float& v, int& i, float vo, int io) {
  if (vo > v || (vo == v && io < i)) { v = vo; i = io; }
}

__device__ __forceinline__ void amax_sh(float& v, int& i, int m) {
  float vo = __shfl_xor(v, m);
  int io = __shfl_xor(i, m);
  amax_comb(v, i, vo, io);
}

#if __has_builtin(__builtin_amdgcn_mov_dpp)
#define HAVE_DPP 1
template <int CTRL>
__device__ __forceinline__ void amax_dpp(float& v, int& i) {
  float vo = __int_as_float(
      __builtin_amdgcn_mov_dpp(__float_as_int(v), CTRL, 0xF, 0xF, true));
  int io = __builtin_amdgcn_mov_dpp(i, CTRL, 0xF, 0xF, true);
  amax_comb(v, i, vo, io);
}
template <int CTRL>
__device__ __forceinline__ float dpp_addf(float x) {
  return x + __int_as_float(
      __builtin_amdgcn_mov_dpp(__float_as_int(x), CTRL, 0xF, 0xF, true));
}
#endif

// argmax (first-index tiebreak) over the 64-lane wave.
// v11: pure-DPP tree — 4 row stages (each lane = its row's argmax, v9/v10
// HW-verified) + row_bcast15 + row_bcast31 => lane 63 holds the wave argmax.
// assoc+comm combine => bit-identical to any tree. ONLY LANE 63 IS VALID.
// (bcast fill lanes 0..15 combine with (0.0,0) garbage — never read.)
__device__ __forceinline__ void wave_amax63(float& v, int& i) {
#ifdef HAVE_DPP
  amax_dpp<0xB1>(v, i);     // quad_perm xor1
  amax_dpp<0x4E>(v, i);     // quad_perm xor2
  amax_dpp<0x124>(v, i);    // row_ror:4
  amax_dpp<0x128>(v, i);    // row_ror:8  -> full 16-lane row argmax, all lanes
  amax_dpp<0x142>(v, i);    // row_bcast15: lane63 = comb(A3, A2)
  amax_dpp<0x143>(v, i);    // row_bcast31: lane63 = comb(comb(A3,A2), comb(A1,A0))
#else
  #pragma unroll
  for (int s = 1; s < 64; s <<= 1) amax_sh(v, i, s);
#endif
}

// full 64-lane sum into LANE 63 ONLY (other lanes garbage).
// lane63 = (A3+A2)+(A1+A0) == (A0+A1)+(A2+A3) (v10's value) by FP-add
// commutativity of each node => Z stays bit-exact vs v10.
__device__ __forceinline__ float wave_sum63(float x) {
#ifdef HAVE_DPP
  x = dpp_addf<0xB1>(x);
  x = dpp_addf<0x4E>(x);
  x = dpp_addf<0x124>(x);
  x = dpp_addf<0x128>(x);
  x = dpp_addf<0x142>(x);   // row_bcast15
  x = dpp_addf<0x143>(x);   // row_bcast31 -> lane 63 = wave total
#else
  #pragma unroll
  for (int s = 1; s < 64; s <<= 1) x += __shfl_xor(x, s);
#endif
  return x;
}

// ---------------------------------------------------------------------------
// K1 (grid 290 x 512 thr):
//   blocks 0..255  : xf0[b] = ar0[b]@W1 + b1 + relu(um[a[b]]@Wf + bf)
//   blocks 256..287: Wq row r = Wp[r]@W1
//   block 288      : cvec = bp@W1
//   block 289      : pack Wk fp32 -> f16 pairs into ws[WS_WK2]
// ---------------------------------------------------------------------------
__global__ __launch_bounds__(512) void suh_prep(
    const float* __restrict__ ar0, const int* __restrict__ act,
    const float* __restrict__ Wf, const float* __restrict__ bfv,
    const float* __restrict__ W1, const float* __restrict__ b1,
    const float* __restrict__ Wp, const float* __restrict__ bp,
    const float* __restrict__ Wk, const float* __restrict__ umt,
    float* __restrict__ ws)
{
  __shared__ float lvec[1024];
  __shared__ float red2[512];
  __shared__ float feL[256];
  __shared__ float lum[256];
  const int t = threadIdx.x;
  const int bid = blockIdx.x;

  if (bid >= 289) {                      // block 289: Wk f16 pack
    half2v* wkp = (half2v*)(ws + WS_WK2);
    #pragma unroll
    for (int i = 0; i < 8; ++i) {
      const int p = t * 8 + i;           // p in [0,4096)
      const int c2 = p >> 5, h = p & 31; // channel pair c2 -> (2c2, 2c2+1)
      half2v v = { (_Float16)Wk[c2 * 64 + h], (_Float16)Wk[c2 * 64 + 32 + h] };
      wkp[p] = v;
    }
    return;
  }

  const int o = t & 255, hf = t >> 8;
  const float* src;
  if (bid < NB) src = ar0 + bid * 1024;
  else if (bid < NB + 32) src = Wp + (bid - NB) * 1024;
  else src = bp;

  for (int i = t; i < 1024; i += 512) lvec[i] = src[i];
  if (bid < NB && t < 256) lum[t] = umt[act[bid] * 256 + t];
  __syncthreads();

  float p = 0.0f;
  const int kb = hf * 512;
  #pragma unroll 16
  for (int k = 0; k < 512; ++k) p = fmaf(lvec[kb + k], W1[(kb + k) * 256 + o], p);
  red2[hf * 256 + o] = p;
  if (bid < NB && hf == 1) {
    float fe = bfv[o];
    #pragma unroll 8
    for (int k = 0; k < 256; ++k) fe = fmaf(lum[k], Wf[k * 256 + o], fe);
    feL[o] = fmaxf(fe, 0.0f);
  }
  __syncthreads();

  if (t < 256) {
    const float s = red2[t] + red2[256 + t];
    if (bid < NB)            ws[WS_XF0 + bid * 256 + t] = s + b1[t] + feL[t];
    else if (bid < NB + 32)  ws[WS_WQ + (bid - NB) * 256 + t] = s;
    else                     ws[WS_CV + t] = s;
  }
}

// ---------------------------------------------------------------------------
// K2: one block per batch row; 64 autoregressive steps, 5 light barriers/step.
// ---------------------------------------------------------------------------
__global__ __launch_bounds__(512, 1) void suh_main(
    const float* __restrict__ ar0, const int* __restrict__ act,
    const float* __restrict__ emb, const float* __restrict__ bk,
    const float* __restrict__ W2, const float* __restrict__ b2,
    const float* __restrict__ Wx, const float* __restrict__ Wh,
    const float* __restrict__ bl, const float* __restrict__ Wp,
    const float* __restrict__ bp, const float* __restrict__ selt,
    const float* __restrict__ ws, float* __restrict__ outp)
{
  const int b = blockIdx.x;
  const int t = threadIdx.x;
  const float sel = selt[act[b]];
  float* outL = outp;
  float* outU = outp + OFF_UNITS;
  float* outA = outp + OFF_AR;

  if (sel == 0.0f) {
    float4 z4 = {0.0f, 0.0f, 0.0f, 0.0f};
    float4* pl = (float4*)(outL + (size_t)b * 32768);
    for (int i = t; i < 8192; i += 512) pl[i] = z4;
    if (t < 16) ((float4*)(outU + b * 64))[t] = z4;
    if (t < 256) ((float4*)(outA + b * 1024))[t] = z4;
    return;
  }

  __shared__ half2v kpT[16][NE];        // 32 KB transposed kp: [h-pair][entity]
  __shared__ float wq[32][256];         // 32 KB Wq = Wp@W1
  __shared__ float xf[256];
  __shared__ float red[512];
  __shared__ float cvs[256];
  __shared__ float sacc[32];
  __shared__ half2v h2b[16];
  __shared__ float gumL[64];            // wave0's gumbels (by wave1)
  __shared__ __align__(16) float wsum[8];
  __shared__ __align__(16) float wargv[8];
  __shared__ __align__(16) int   wargi[8];

  // ---- per-thread register weights (phase A) ------------------------------
  const int hh = t & 31, kc = t >> 5;
  float w2r[16];
  #pragma unroll
  for (int i = 0; i < 16; ++i) w2r[i] = W2[(kc * 16 + i) * 32 + hh];

  float blv0 = 0.0f, blv1 = 0.0f, b2v = 0.0f;
  float hv = 0.0f, cv = 0.0f;           // LSTM state in wave0 lanes 0..31
  if (t < 64) { blv0 = bl[t]; blv1 = bl[64 + t]; b2v = b2[t & 31]; }

  // ---- LSTM weights into wave0 registers (f16 pairs {Wx,Wh}) --------------
  half2v w0r[32], w1r[32];
  if (t < 64) {
    #pragma unroll
    for (int r = 0; r < 32; ++r) {
      w0r[r] = half2v{ (_Float16)Wx[r * 128 + t],      (_Float16)Wh[r * 128 + t] };
      w1r[r] = half2v{ (_Float16)Wx[r * 128 + 64 + t], (_Float16)Wh[r * 128 + 64 + t] };
    }
  }

  // ---- LDS fills ----------------------------------------------------------
  {
    const float4* s4 = (const float4*)(ws + WS_WQ);
    float4* d4 = (float4*)&wq[0][0];
    for (int i = t; i < 2048; i += 512) d4[i] = s4[i];
  }
  if (t < 256) { xf[t] = ws[WS_XF0 + b * 256 + t]; cvs[t] = ws[WS_CV + t]; }
  if (t < 32) sacc[t] = 0.0f;
  float mymask = 1.0f;                  // register mask (v8-proven)

  // ---- key_proj row e=t via fdot2, written transposed; keep kpr in VGPRs --
  half2v kpr[16];
  {
    float acc[32];
    #pragma unroll
    for (int h = 0; h < 32; ++h) acc[h] = bk[h];
    const float4* erow = (const float4*)(emb + (size_t)b * (NE * 256) + (size_t)t * 256);
    const half2v* wkg = (const half2v*)(ws + WS_WK2);
    for (int c4 = 0; c4 < 64; ++c4) {
      float4 ev = erow[c4];
      half2v e01 = { (_Float16)ev.x, (_Float16)ev.y };
      half2v e23 = { (_Float16)ev.z, (_Float16)ev.w };
      const half2v* w0 = wkg + (2 * c4) * 32;
      const half2v* w1 = w0 + 32;
      #pragma unroll
      for (int h = 0; h < 32; ++h) {
        acc[h] = fdot2f(e01, w0[h], acc[h]);
        acc[h] = fdot2f(e23, w1[h], acc[h]);
      }
    }
    #pragma unroll
    for (int j = 0; j < 16; ++j) {
      half2v v = { (_Float16)acc[2 * j], (_Float16)acc[2 * j + 1] };
      kpr[j] = v;
      kpT[j][t] = v;
    }
  }
  __syncthreads();

  for (int step = 0; step < NT; ++step) {
    // ---- A: z2 partials: relu(xf) @ W2 ------------------------------------
    {
      float pa = 0.0f;
      const float* xk = &xf[kc * 16];
      #pragma unroll
      for (int i = 0; i < 16; ++i) pa = fmaf(fmaxf(xk[i], 0.0f), w2r[i], pa);
      red[kc * 32 + hh] = pa;
    }
    BARL();                                            // B1

    // ---- B: wave0: z2 reduce + LSTM (VGPR weights, readlane bcast) --------
    if (t < 64) {
      const int h = t & 31, half = t >> 5;
      float z = 0.0f;
      #pragma unroll
      for (int i = 0; i < 8; ++i) z += red[(half * 8 + i) * 32 + h];
      z += __shfl_xor(z, 32);
      const float z2v = z + b2v;

      float g0 = blv0, g1 = blv1;
      #pragma unroll
      for (int r = 0; r < 32; ++r) {
        const float zr = rlf(z2v, r);
        const float hr = rlf(hv, r);
        half2v p0 = w0r[r];
        half2v p1 = w1r[r];
        g0 = fmaf(zr, (float)p0.x, g0); g0 = fmaf(hr, (float)p0.y, g0);
        g1 = fmaf(zr, (float)p1.x, g1); g1 = fmaf(hr, (float)p1.y, g1);
      }
      const float zf = __shfl_xor(g0, 32);
      const float zo = __shfl_xor(g1, 32);
      if (t < 32) {
        const float si = sigm_f(g0);
        const float sf = sigm_f(zf);
        const float so = sigm_f(zo);
        cv = sf * cv + si * tanh_f(g1);
        hv = so * tanh_f(cv);
      }
      const float ha = __shfl(hv, 2 * (t & 31));
      const float hb = __shfl(hv, 2 * (t & 31) + 1);
      if (t < 16) { half2v v = { (_Float16)ha, (_Float16)hb }; h2b[t] = v; }
    }

    // ---- inline gumbel for waves 1..7, hidden under wave0's phase B.
    // Wave1 also produces wave0's 64 draws into gumL (visible after B2).
    float gum = 0.0f;
    if (t >= 64) {
      gum = gumbel_draw(SUBTAB.s0[step], SUBTAB.s1[step], (u32)(b * 512 + t));
      if (t < 128)
        gumL[t - 64] = gumbel_draw(SUBTAB.s0[step], SUBTAB.s1[step],
                                   (u32)(b * 512 + (t - 64)));
    }
    BARL();                                            // B2

    // ---- C: logits (register kp row), exp, DPP wave sum (lane63) ----------
    float a0 = 0.0f, a1 = 0.0f, a2 = 0.0f, a3 = 0.0f;
    #pragma unroll
    for (int j = 0; j < 16; j += 4) {
      a0 = fdot2f(kpr[j],     h2b[j],     a0);
      a1 = fdot2f(kpr[j + 1], h2b[j + 1], a1);
      a2 = fdot2f(kpr[j + 2], h2b[j + 2], a2);
      a3 = fdot2f(kpr[j + 3], h2b[j + 3], a3);
    }
    const float y2 = ((a0 + a1) + (a2 + a3)) * mymask;
    outL[(size_t)b * 32768 + step * 512 + t] = y2;
    const float ev = __expf(y2);
    float sv = wave_sum63(ev);
    if ((t & 63) == 63) wsum[t >> 6] = sv;             // v11: lane 63 valid
    BARL();                                            // B3

    if (t < 64) gum = gumL[t];                         // wave0 draws
    float Z;
    {
      const f4* wz = (const f4*)wsum;                  // b128 loads, v10 order
      f4 za = wz[0], zb = wz[1];
      Z = ((((((za.x + za.y) + za.z) + za.w) + zb.x) + zb.y) + zb.z) + zb.w;
    }
    float val = ev / Z + gum;
    int idx = t;
    wave_amax63(val, idx);                             // v11: lane 63 valid
    if ((t & 63) == 63) { wargv[t >> 6] = val; wargi[t >> 6] = idx; }
    BARL();                                            // B4

    float bvv; int id;
    {
      const f4* wv4 = (const f4*)wargv;                // b128 loads, v10 order
      const i32x4* wi4 = (const i32x4*)wargi;
      f4 va = wv4[0], vb = wv4[1];
      i32x4 ia = wi4[0], ib = wi4[1];
      bvv = va.x; id = ia.x;
      amax_comb(bvv, id, va.y, ia.y);
      amax_comb(bvv, id, va.z, ia.z);
      amax_comb(bvv, id, va.w, ia.w);
      amax_comb(bvv, id, vb.x, ib.x);
      amax_comb(bvv, id, vb.y, ib.y);
      amax_comb(bvv, id, vb.z, ib.z);
      amax_comb(bvv, id, vb.w, ib.w);
    }

    // ---- D: mask, outputs, xf feedback ------------------------------------
    if (t == id) mymask = 0.0f;
    if (t == 0) outU[b * 64 + step] = (float)id;
    if (t < 32) {
      half2v kj = kpT[t >> 1][id];
      const float kv = (t & 1) ? (float)kj.y : (float)kj.x;
      sacc[t] += kv - 0.001953125f;
    }
    if (t < 256) {
      float dx = cvs[t];
      #pragma unroll
      for (int j = 0; j < 16; ++j) {
        half2v kj = kpT[j][id];
        dx = fmaf((float)kj.x - 0.001953125f, wq[2 * j][t], dx);
        dx = fmaf((float)kj.y - 0.001953125f, wq[2 * j + 1][t], dx);
      }
      xf[t] += dx;
    }
    BARL();                                            // B5
  }

  // ---- epilogue: ar = ar0 + sacc@Wp + 64*bp -------------------------------
  for (int j = t; j < 1024; j += 512) {
    float acc2 = ar0[b * 1024 + j] + 64.0f * bp[j];
    #pragma unroll 8
    for (int r = 0; r < 32; ++r) acc2 = fmaf(sacc[r], Wp[r * 1024 + j], acc2);
    outA[b * 1024 + j] = acc2;
  }
}

extern "C" void kernel_launch(void* const* d_in, const int* in_sizes, int n_in,
                              void* d_out, int out_size, void* d_ws, size_t ws_size,
                              hipStream_t stream)
{
  (void)in_sizes; (void)n_in; (void)out_size; (void)ws_size;
  const float* ar0 = (const float*)d_in[0];
  const int*   act = (const int*)d_in[1];
  const float* emb = (const float*)d_in[2];
  const float* Wf  = (const float*)d_in[3];
  const float* bfv = (const float*)d_in[4];
  const float* Wk  = (const float*)d_in[5];
  const float* bk  = (const float*)d_in[6];
  const float* W1  = (const float*)d_in[7];
  const float* b1  = (const float*)d_in[8];
  const float* W2  = (const float*)d_in[9];
  const float* b2  = (const float*)d_in[10];
  const float* Wx  = (const float*)d_in[11];
  const float* Wh  = (const float*)d_in[12];
  const float* bl  = (const float*)d_in[13];
  const float* Wp  = (const float*)d_in[14];
  const float* bp  = (const float*)d_in[15];
  const float* umt = (const float*)d_in[16];
  const float* selt = (const float*)d_in[17];
  float* ws = (float*)d_ws;
  float* outp = (float*)d_out;

  suh_prep<<<dim3(290), dim3(512), 0, stream>>>(ar0, act, Wf, bfv, W1, b1, Wp, bp, Wk, umt, ws);
  suh_main<<<dim3(256), dim3(512), 0, stream>>>(ar0, act, emb, bk, W2, b2, Wx, Wh,
                                                bl, Wp, bp, selt, ws, outp);
}